// Round 16
// baseline (498.026 us; speedup 1.0000x reference)
//
#include <hip/hip_runtime.h>

#define DIM 64
#define XS_STRIDE 192
#define BN_EPS 1e-5f
#define B_MAX 512          // max dst buckets (N up to 131072 at W=256)
#define P4_CAP 6144        // LDS staging cap per bucket (mean 4092, 32 sigma)
#define CSR_CHUNK 8192     // edges per partition block (196 blocks at E=1.6M)
#define BSPACE 1280        // per-bucket extra padded space (>= 1024 + slack)

__device__ inline unsigned pack_bf16x2(float lo, float hi) {
    unsigned ulo = __float_as_uint(lo); ulo = (ulo + 0x7FFFu + ((ulo >> 16) & 1u)) >> 16;
    unsigned uhi = __float_as_uint(hi); uhi = (uhi + 0x7FFFu + ((uhi >> 16) & 1u)) >> 16;
    return ulo | (uhi << 16);
}
__device__ inline float2 unpack_bf16x2(unsigned v) {
    return make_float2(__uint_as_float(v << 16), __uint_as_float(v & 0xFFFF0000u));
}

// ---- merged: blocks [0,NB1) = bucket histogram (+setup in block 0);
//      blocks [NB1, NB1+pblocks) = proj0 (y = x @ w1, bf16x2 packed) ----
__global__ __launch_bounds__(256) void p1proj_kernel(
    const int* __restrict__ dsts, long long E, int NB1, int B, int* __restrict__ bh,
    float* __restrict__ stats,
    const float* __restrict__ x, int F_IN,
    const float* __restrict__ w1, unsigned* __restrict__ ybf, int N)
{
    __shared__ int hist[B_MAX];
    __shared__ float w1s[128 * DIM];     // 32KB
    __shared__ float hin[32][128];       // 16KB
    const int t = threadIdx.x;

    if (blockIdx.x < NB1) {
        const int i = blockIdx.x;
        if (i == 0) {
            for (int k = t; k < 3 * 256; k += 256) stats[k] = 0.f;
            if (t < 32) ybf[(size_t)N * 32 + t] = 0u;   // zero row for gap gathers
        }
        for (int b = t; b < B; b += 256) hist[b] = 0;
        __syncthreads();
        long long s0 = (long long)i * CSR_CHUNK;
        long long s1 = s0 + CSR_CHUNK; if (s1 > E) s1 = E;
        if (s1 - s0 == CSR_CHUNK) {
            const int4* d4 = (const int4*)(dsts + s0);
            #pragma unroll
            for (int k = 0; k < CSR_CHUNK / 1024; k++) {   // 8 int4 per thread
                int4 v = d4[k * 256 + t];
                atomicAdd(&hist[v.x >> 8], 1);
                atomicAdd(&hist[v.y >> 8], 1);
                atomicAdd(&hist[v.z >> 8], 1);
                atomicAdd(&hist[v.w >> 8], 1);
            }
        } else {
            for (long long e = s0 + t; e < s1; e += 256)
                atomicAdd(&hist[dsts[e] >> 8], 1);
        }
        __syncthreads();
        for (int b = t; b < B; b += 256) bh[b * NB1 + i] = hist[b];
        return;
    }
    // ---------- proj0: y = x @ w1 (DIN=128) ----------
    const int row0 = (blockIdx.x - NB1) * 32;
    for (int i = t; i < 128 * DIM / 4; i += 256)
        *(float4*)&w1s[i * 4] = *(const float4*)&w1[i * 4];
    for (int i = t; i < 32 * 128 / 4; i += 256) {
        int r = i / 32, k4 = (i % 32) * 4;
        int row = row0 + r;
        float4 hv = make_float4(0.f, 0.f, 0.f, 0.f);
        if (row < N) hv = *(const float4*)&x[(size_t)row * F_IN + k4];
        *(float4*)&hin[r][k4] = hv;
    }
    __syncthreads();

    const int hw = t >> 5;
    const int hl = t & 31;
    float a0[4], a1[4];
    #pragma unroll
    for (int q = 0; q < 4; q++) { a0[q] = 0.f; a1[q] = 0.f; }
    for (int k = 0; k < 128; k++) {
        float w0 = w1s[k * DIM + 2 * hl];
        float w1v = w1s[k * DIM + 2 * hl + 1];
        #pragma unroll
        for (int q = 0; q < 4; q++) {
            float hv = hin[hw * 4 + q][k];
            a0[q] += hv * w0; a1[q] += hv * w1v;
        }
    }
    #pragma unroll
    for (int q = 0; q < 4; q++) {
        int row = row0 + hw * 4 + q;
        if (row < N) ybf[(size_t)row * 32 + hl] = pack_bf16x2(a0[q], a1[q]);
    }
}

// ---------------- P2: one-block exclusive scan of bh[B*NB1] ----------------
__global__ __launch_bounds__(1024) void p2_scan(int* __restrict__ bh, int total_n) {
    __shared__ int sbuf[2][1024];
    const int t = threadIdx.x;
    const int seg = (total_n + 1023) / 1024;
    int s0 = t * seg, s1 = s0 + seg; if (s1 > total_n) s1 = total_n;
    int s = 0;
    for (int i = s0; i < s1; i++) s += bh[i];
    sbuf[0][t] = s; __syncthreads();
    int c = 0;
    for (int o = 1; o < 1024; o <<= 1) {
        int val = sbuf[c][t];
        if (t >= o) val += sbuf[c][t - o];
        sbuf[c ^ 1][t] = val; __syncthreads(); c ^= 1;
    }
    int run = sbuf[c][t] - s;
    for (int i = s0; i < s1; i++) { int v = bh[i]; bh[i] = run; run += v; }
}

// ---------------- P3: partition edges into bucket runs (block-private, dense) ----------------
__global__ __launch_bounds__(256) void p3_part(const int* __restrict__ edges, long long E,
                                               int NB1, int B, const int* __restrict__ bh,
                                               unsigned* __restrict__ ebuf) {
    __shared__ int cur[B_MAX];
    const int i = blockIdx.x, t = threadIdx.x;
    for (int b = t; b < B; b += 256) cur[b] = bh[b * NB1 + i];
    __syncthreads();
    long long s0 = (long long)i * CSR_CHUNK;
    long long s1 = s0 + CSR_CHUNK; if (s1 > E) s1 = E;
    for (long long e = s0 + t; e < s1; e += 256) {
        int src = edges[e];
        int dst = edges[E + e];
        int b = dst >> 8;
        int pos = atomicAdd(&cur[b], 1);
        ebuf[pos] = (unsigned)src | ((unsigned)(dst & 255) << 24);
    }
}

// ---- P4: per-bucket padded CSR: node runs padded to mult-of-4 (min 4), gaps = N ----
__global__ __launch_bounds__(256) void p4_build(const unsigned* __restrict__ ebuf, long long E,
                                                int NB1, int B, const int* __restrict__ bh,
                                                int* __restrict__ offsets, int* __restrict__ psz,
                                                int* __restrict__ eidx, int N) {
    __shared__ unsigned lbuf[P4_CAP];
    __shared__ int hist[256];
    __shared__ int sbuf[2][256];
    __shared__ int cur[256];
    __shared__ int lstart[256];
    const int b = blockIdx.x, t = threadIdx.x;
    const int s = bh[b * NB1];
    const int e = (b + 1 < B) ? bh[(b + 1) * NB1] : (int)E;
    const int sz = e - s;
    const int ps = ((s + 3) & ~3) + b * BSPACE;
    const int next_raw = (b + 1 < B) ? bh[(b + 1) * NB1] : (int)E;
    const int next_ps = ((next_raw + 3) & ~3) + (b + 1) * BSPACE;
    const bool inl = (sz <= P4_CAP);
    if (inl) for (int k = t; k < sz; k += 256) lbuf[k] = ebuf[s + k];
    hist[t] = 0;
    __syncthreads();
    for (int k = t; k < sz; k += 256) {
        unsigned v = inl ? lbuf[k] : ebuf[s + k];
        atomicAdd(&hist[v >> 24], 1);
    }
    __syncthreads();
    const int deg = hist[t];
    const int pad = max(4, (deg + 3) & ~3);
    sbuf[0][t] = pad; __syncthreads();
    int c = 0;
    for (int o = 1; o < 256; o <<= 1) {
        int val = sbuf[c][t];
        if (t >= o) val += sbuf[c][t - o];
        sbuf[c ^ 1][t] = val; __syncthreads(); c ^= 1;
    }
    const int excl = sbuf[c][t] - pad;
    const int total = sbuf[c][255];
    const int node = b * 256 + t;
    if (node < N) { offsets[node] = ps + excl; psz[node] = pad; }
    lstart[t] = excl;
    cur[t] = 0;
    __syncthreads();
    for (int k = t; k < sz; k += 256) {
        unsigned v = inl ? lbuf[k] : ebuf[s + k];
        int dl = v >> 24;
        int pos = atomicAdd(&cur[dl], 1);
        eidx[ps + lstart[dl] + pos] = (int)(v & 0xFFFFFFu);
    }
    for (int k = deg; k < pad; k++) eidx[ps + excl + k] = N;
    __syncthreads();
    for (int i = ps + total + t; i < next_ps; i += 256) eidx[i] = N;
}

// ---- y = h @ w1 (bf16x2); FUSE: prev-layer BN computed inline + write back ----
template<int DIN, bool FUSE>
__global__ __launch_bounds__(256) void proj_kernel(
    const float* __restrict__ h, int h_stride, int h_off,
    float* __restrict__ h_back,
    const float* __restrict__ w1,
    const float* __restrict__ stats_prev,
    const float* __restrict__ gamma_prev, const float* __restrict__ beta_prev,
    unsigned* __restrict__ ybf, int N)
{
    constexpr int R = 32;
    __shared__ float w1s[DIN * DIM];
    __shared__ float hin[R][DIN];
    __shared__ float scshs[2 * DIM];
    const int tid = threadIdx.x;
    const int row0 = blockIdx.x * R;

    if (FUSE && tid < DIM) {
        float inv_n = 1.0f / (float)N;
        float mean = stats_prev[tid] * inv_n;
        float var  = stats_prev[DIM + tid] * inv_n - mean * mean;
        float sc   = gamma_prev[tid] * rsqrtf(var + BN_EPS);
        scshs[tid] = sc;
        scshs[DIM + tid] = beta_prev[tid] - mean * sc;
    }
    for (int i = tid; i < DIN * DIM / 4; i += 256)
        *(float4*)&w1s[i * 4] = *(const float4*)&w1[i * 4];
    if (FUSE) __syncthreads();
    for (int i = tid; i < R * DIN / 4; i += 256) {
        int r = i / (DIN / 4), k4 = (i % (DIN / 4)) * 4;
        int row = row0 + r;
        float4 hv = make_float4(0.f, 0.f, 0.f, 0.f);
        if (row < N) {
            hv = *(const float4*)&h[(size_t)row * h_stride + h_off + k4];
            if (FUSE) {
                hv.x = hv.x * scshs[k4 + 0] + scshs[DIM + k4 + 0];
                hv.y = hv.y * scshs[k4 + 1] + scshs[DIM + k4 + 1];
                hv.z = hv.z * scshs[k4 + 2] + scshs[DIM + k4 + 2];
                hv.w = hv.w * scshs[k4 + 3] + scshs[DIM + k4 + 3];
                *(float4*)&h_back[(size_t)row * h_stride + h_off + k4] = hv;
            }
        }
        *(float4*)&hin[r][k4] = hv;
    }
    __syncthreads();

    const int hw = tid >> 5;
    const int hl = tid & 31;
    float a0[4], a1[4];
    #pragma unroll
    for (int q = 0; q < 4; q++) { a0[q] = 0.f; a1[q] = 0.f; }
    for (int k = 0; k < DIN; k++) {
        float w0 = w1s[k * DIM + 2 * hl];
        float w1v = w1s[k * DIM + 2 * hl + 1];
        #pragma unroll
        for (int q = 0; q < 4; q++) {
            float hv = hin[hw * 4 + q][k];
            a0[q] += hv * w0; a1[q] += hv * w1v;
        }
    }
    #pragma unroll
    for (int q = 0; q < 4; q++) {
        int row = row0 + hw * 4 + q;
        if (row < N) ybf[(size_t)row * 32 + hl] = pack_bf16x2(a0[q], a1[q]);
    }
}

// ---- fused agg+MLP (quarter-wave, pipelined); optional merged poolA blocks ----
template<bool WITH_POOL>
__global__ __launch_bounds__(256) void aggmlp_kernel(
    const unsigned* __restrict__ ybf,
    const int* __restrict__ offsets, const int* __restrict__ psz,
    const int* __restrict__ eidx,
    const float* __restrict__ b1,
    const float* __restrict__ w2, const float* __restrict__ b2,
    float* __restrict__ xs, int xs_off,
    float* __restrict__ stats, int N,
    int ablocks, const int* __restrict__ batch, float* __restrict__ pool)
{
    constexpr int R = 64;
    __shared__ float zin[R][DIM];        // 16KB
    __shared__ float sred[2][DIM];
    const int tid  = threadIdx.x;

    if (WITH_POOL && blockIdx.x >= ablocks) {
        // ---------- poolA: sum cols 0..127 (already normalized) per graph ----------
        const int g = blockIdx.x - ablocks;
        const int half = tid >> 7, c = tid & 127;
        int lo = 0, hi = N;
        while (lo < hi) { int mid = (lo + hi) >> 1; if (batch[mid] < g) lo = mid + 1; else hi = mid; }
        int start = lo;
        hi = N;
        while (lo < hi) { int mid = (lo + hi) >> 1; if (batch[mid] < g + 1) lo = mid + 1; else hi = mid; }
        int end = lo;
        int mid2 = (start + end) >> 1;
        int rs = half ? mid2 : start;
        int re = half ? end : mid2;
        float s = 0.f;
        for (int n = rs; n < re; n++) s += xs[(size_t)n * XS_STRIDE + c];
        __shared__ float psum[2][128];
        psum[half][c] = s;
        __syncthreads();
        if (half == 0) pool[(size_t)g * XS_STRIDE + c] = psum[0][c] + psum[1][c];
        return;
    }

    const int row0 = blockIdx.x * R;
    const int qw = tid >> 4;
    const int ql = tid & 15;
    const uint2* __restrict__ ybf2 = (const uint2*)ybf;

    if (tid < DIM) { sred[0][tid] = 0.f; sred[1][tid] = 0.f; }

    const float4 b1v = *(const float4*)&b1[ql * 4];
    int p0[4], sz[4];
    float ac[4][4];
    #pragma unroll
    for (int q = 0; q < 4; q++) {
        int node = row0 + qw * 4 + q;
        if (node < N) {
            p0[q] = offsets[node];
            sz[q] = psz[node];
            uint2 sv = ybf2[(size_t)node * 16 + ql];
            float2 lo = unpack_bf16x2(sv.x), hi = unpack_bf16x2(sv.y);
            ac[q][0] = lo.x + b1v.x; ac[q][1] = lo.y + b1v.y;
            ac[q][2] = hi.x + b1v.z; ac[q][3] = hi.y + b1v.w;
        } else {
            p0[q] = 0; sz[q] = 0;
            ac[q][0] = ac[q][1] = ac[q][2] = ac[q][3] = 0.f;
        }
    }
    int steps = 0;
    #pragma unroll
    for (int q = 0; q < 4; q++) steps = max(steps, sz[q] >> 2);

    int4 e4[4];
    #pragma unroll
    for (int q = 0; q < 4; q++)
        e4[q] = *(const int4*)&eidx[p0[q]];

    for (int s = 0; s < steps; s++) {
        const int b4 = 4 * s;
        uint2 g[4][4];
        #pragma unroll
        for (int q = 0; q < 4; q++) {
            g[q][0] = ybf2[(size_t)e4[q].x * 16 + ql];
            g[q][1] = ybf2[(size_t)e4[q].y * 16 + ql];
            g[q][2] = ybf2[(size_t)e4[q].z * 16 + ql];
            g[q][3] = ybf2[(size_t)e4[q].w * 16 + ql];
        }
        int4 e4n[4];
        #pragma unroll
        for (int q = 0; q < 4; q++) {
            int off = max(0, min(b4 + 4, sz[q] - 4));
            e4n[q] = *(const int4*)&eidx[p0[q] + off];
        }
        #pragma unroll
        for (int q = 0; q < 4; q++) {
            const float m = (b4 < sz[q]) ? 1.f : 0.f;
            #pragma unroll
            for (int j = 0; j < 4; j++) {
                float2 lo = unpack_bf16x2(g[q][j].x), hi = unpack_bf16x2(g[q][j].y);
                ac[q][0] += lo.x * m; ac[q][1] += lo.y * m;
                ac[q][2] += hi.x * m; ac[q][3] += hi.y * m;
            }
        }
        #pragma unroll
        for (int q = 0; q < 4; q++) e4[q] = e4n[q];
    }
    #pragma unroll
    for (int q = 0; q < 4; q++) {
        int r = qw * 4 + q;
        float4 z;
        z.x = fmaxf(ac[q][0], 0.f); z.y = fmaxf(ac[q][1], 0.f);
        z.z = fmaxf(ac[q][2], 0.f); z.w = fmaxf(ac[q][3], 0.f);
        *(float4*)&zin[r][ql * 4] = z;
    }
    __syncthreads();

    const int lane = tid & 63;
    const int wv_  = tid >> 6;
    float oacc[16];
    #pragma unroll
    for (int i = 0; i < 16; i++) oacc[i] = b2[lane];
    for (int k = 0; k < DIM; k++) {
        float w = w2[k * DIM + lane];
        #pragma unroll
        for (int i = 0; i < 16; i++) oacc[i] += zin[wv_ + 4 * i][k] * w;
    }
    float s1 = 0.f, s2 = 0.f;
    #pragma unroll
    for (int i = 0; i < 16; i++) {
        int row = row0 + wv_ + 4 * i;
        if (row < N) {
            float v = fmaxf(oacc[i], 0.f);
            xs[(size_t)row * XS_STRIDE + xs_off + lane] = v;
            s1 += v; s2 += v * v;
        }
    }
    atomicAdd(&sred[0][lane], s1);
    atomicAdd(&sred[1][lane], s2);
    __syncthreads();
    if (tid < DIM) {
        atomicAdd(&stats[tid], sred[0][tid]);
        atomicAdd(&stats[DIM + tid], sred[1][tid]);
    }
}

// ---- poolB: cols 128..191 with layer-2 BN computed inline + write-back ----
__global__ void poolB_kernel(float* __restrict__ xs, const int* __restrict__ batch,
                             float* __restrict__ pool,
                             const float* __restrict__ stats2,
                             const float* __restrict__ gamma2, const float* __restrict__ beta2,
                             int N) {
    int g = blockIdx.x;
    int c = threadIdx.x;  // 64 threads
    float inv_n = 1.0f / (float)N;
    float mean = stats2[c] * inv_n;
    float var  = stats2[DIM + c] * inv_n - mean * mean;
    float sc = gamma2[c] * rsqrtf(var + BN_EPS);
    float sh = beta2[c] - mean * sc;
    int lo = 0, hi = N;
    while (lo < hi) { int mid = (lo + hi) >> 1; if (batch[mid] < g) lo = mid + 1; else hi = mid; }
    int start = lo;
    hi = N;
    while (lo < hi) { int mid = (lo + hi) >> 1; if (batch[mid] < g + 1) lo = mid + 1; else hi = mid; }
    int end = lo;
    float s = 0.f;
    for (int n = start; n < end; n++) {
        size_t p = (size_t)n * XS_STRIDE + 2 * DIM + c;
        float v = xs[p] * sc + sh;
        xs[p] = v;
        s += v;
    }
    pool[(size_t)g * XS_STRIDE + 2 * DIM + c] = s;
}

extern "C" void kernel_launch(void* const* d_in, const int* in_sizes, int n_in,
                              void* d_out, int out_size, void* d_ws, size_t ws_size,
                              hipStream_t stream) {
    const float* x     = (const float*)d_in[0];
    const int*   edges = (const int*)d_in[1];   // int32 (harness converts integer inputs)
    const int*   batch = (const int*)d_in[2];   // int32

    const int  N    = in_sizes[2];
    const long long E = in_sizes[1] / 2;
    const int  F_IN = in_sizes[0] / N;              // 128
    const int  G    = out_size / XS_STRIDE - N;     // 1000

    const float* W[3][6];
    for (int l = 0; l < 3; l++)
        for (int p = 0; p < 6; p++)
            W[l][p] = (const float*)d_in[4 + l * 6 + p];

    float* out_pool = (float*)d_out;                        // G x 192
    float* out_xs   = out_pool + (size_t)G * XS_STRIDE;     // N x 192

    const int B   = (N + 255) >> 8;
    const int NB1 = (int)((E + CSR_CHUNK - 1) / CSR_CHUNK);
    const int EPAD = (int)(((E + 3) & ~3LL) + (long long)B * BSPACE + 64);

    // workspace layout (~27 MB)
    unsigned* ybf  = (unsigned*)d_ws;                   // (N+1) x 32 u32 (12.8 MB)
    float* stats   = (float*)(ybf + (size_t)(N + 1) * 32);  // 3 x 256 floats
    int*   offsets = (int*)(stats + 3 * 256);           // N
    int*   psz     = offsets + N + 1;                   // N
    int*   eidx    = psz + N;                           // EPAD (~7 MB)
    unsigned* ebuf = (unsigned*)(eidx + EPAD);          // E (6.4 MB)
    int*   bh      = (int*)(ebuf + E);                  // B * NB1 (~300 KB)

    const int pblocks = (N + 31) / 32;
    const int ablocks = (N + 63) / 64;

    // ---- CSR build; proj0 merged into the (underparallel) P1 dispatch ----
    p1proj_kernel<<<NB1 + pblocks, 256, 0, stream>>>(edges + E, E, NB1, B, bh, stats,
                                                     x, F_IN, W[0][0], ybf, N);
    p2_scan<<<1, 1024, 0, stream>>>(bh, B * NB1);
    p3_part<<<NB1, 256, 0, stream>>>(edges, E, NB1, B, bh, ebuf);
    p4_build<<<B, 256, 0, stream>>>(ebuf, E, NB1, B, bh, offsets, psz, eidx, N);

    // layer 0
    aggmlp_kernel<false><<<ablocks, 256, 0, stream>>>(ybf, offsets, psz, eidx,
        W[0][1], W[0][2], W[0][3], out_xs, 0, stats, N, ablocks, nullptr, nullptr);

    // layer 1
    proj_kernel<64, true><<<pblocks, 256, 0, stream>>>(
        out_xs, XS_STRIDE, 0, out_xs, W[1][0], stats, W[0][4], W[0][5], ybf, N);
    aggmlp_kernel<false><<<ablocks, 256, 0, stream>>>(ybf, offsets, psz, eidx,
        W[1][1], W[1][2], W[1][3], out_xs, DIM, stats + 256, N, ablocks, nullptr, nullptr);

    // layer 2 (+ poolA merged: cols 0..127 of per-graph sums)
    proj_kernel<64, true><<<pblocks, 256, 0, stream>>>(
        out_xs, XS_STRIDE, DIM, out_xs, W[2][0], stats + 256, W[1][4], W[1][5], ybf, N);
    aggmlp_kernel<true><<<ablocks + G, 256, 0, stream>>>(ybf, offsets, psz, eidx,
        W[2][1], W[2][2], W[2][3], out_xs, 2 * DIM, stats + 512, N, ablocks, batch, out_pool);

    // remaining pool cols 128..191 (need layer-2 stats)
    poolB_kernel<<<G, DIM, 0, stream>>>(out_xs, batch, out_pool,
                                        stats + 512, W[2][4], W[2][5], N);
}

// Round 17
// 382.312 us; speedup vs baseline: 1.3027x; 1.3027x over previous
//
#include <hip/hip_runtime.h>

#define DIM 64
#define XS_STRIDE 192
#define BN_EPS 1e-5f
#define B_MAX 512          // max dst buckets (N up to 131072 at W=256)
#define P4_CAP 6144        // LDS staging cap per bucket (mean 4092, 32 sigma)
#define CSR_CHUNK 8192     // edges per partition block (196 blocks at E=1.6M)
#define BSPACE 1280        // per-bucket extra padded space (>= 1024 + slack)

__device__ inline unsigned pack_bf16x2(float lo, float hi) {
    unsigned ulo = __float_as_uint(lo); ulo = (ulo + 0x7FFFu + ((ulo >> 16) & 1u)) >> 16;
    unsigned uhi = __float_as_uint(hi); uhi = (uhi + 0x7FFFu + ((uhi >> 16) & 1u)) >> 16;
    return ulo | (uhi << 16);
}
__device__ inline float2 unpack_bf16x2(unsigned v) {
    return make_float2(__uint_as_float(v << 16), __uint_as_float(v & 0xFFFF0000u));
}

// ---- merged: blocks [0,NB1) = bucket histogram (+setup in block 0);
//      blocks [NB1, NB1+pblocks) = proj0 (y = x @ w1, bf16x2 packed) ----
__global__ __launch_bounds__(256) void p1proj_kernel(
    const int* __restrict__ dsts, long long E, int NB1, int B, int* __restrict__ bh,
    float* __restrict__ stats,
    const float* __restrict__ x, int F_IN,
    const float* __restrict__ w1, unsigned* __restrict__ ybf, int N)
{
    __shared__ int hist[B_MAX];
    __shared__ float w1s[128 * DIM];     // 32KB
    __shared__ float hin[32][128];       // 16KB
    const int t = threadIdx.x;

    if (blockIdx.x < NB1) {
        const int i = blockIdx.x;
        if (i == 0) {
            for (int k = t; k < 3 * 256; k += 256) stats[k] = 0.f;
            if (t < 32) ybf[(size_t)N * 32 + t] = 0u;   // zero row for gap gathers
        }
        for (int b = t; b < B; b += 256) hist[b] = 0;
        __syncthreads();
        long long s0 = (long long)i * CSR_CHUNK;
        long long s1 = s0 + CSR_CHUNK; if (s1 > E) s1 = E;
        if (s1 - s0 == CSR_CHUNK) {
            const int4* d4 = (const int4*)(dsts + s0);
            #pragma unroll
            for (int k = 0; k < CSR_CHUNK / 1024; k++) {   // 8 int4 per thread
                int4 v = d4[k * 256 + t];
                atomicAdd(&hist[v.x >> 8], 1);
                atomicAdd(&hist[v.y >> 8], 1);
                atomicAdd(&hist[v.z >> 8], 1);
                atomicAdd(&hist[v.w >> 8], 1);
            }
        } else {
            for (long long e = s0 + t; e < s1; e += 256)
                atomicAdd(&hist[dsts[e] >> 8], 1);
        }
        __syncthreads();
        for (int b = t; b < B; b += 256) bh[b * NB1 + i] = hist[b];
        return;
    }
    // ---------- proj0: y = x @ w1 (DIN=128) ----------
    const int row0 = (blockIdx.x - NB1) * 32;
    for (int i = t; i < 128 * DIM / 4; i += 256)
        *(float4*)&w1s[i * 4] = *(const float4*)&w1[i * 4];
    for (int i = t; i < 32 * 128 / 4; i += 256) {
        int r = i / 32, k4 = (i % 32) * 4;
        int row = row0 + r;
        float4 hv = make_float4(0.f, 0.f, 0.f, 0.f);
        if (row < N) hv = *(const float4*)&x[(size_t)row * F_IN + k4];
        *(float4*)&hin[r][k4] = hv;
    }
    __syncthreads();

    const int hw = t >> 5;
    const int hl = t & 31;
    float a0[4], a1[4];
    #pragma unroll
    for (int q = 0; q < 4; q++) { a0[q] = 0.f; a1[q] = 0.f; }
    for (int k = 0; k < 128; k++) {
        float w0 = w1s[k * DIM + 2 * hl];
        float w1v = w1s[k * DIM + 2 * hl + 1];
        #pragma unroll
        for (int q = 0; q < 4; q++) {
            float hv = hin[hw * 4 + q][k];
            a0[q] += hv * w0; a1[q] += hv * w1v;
        }
    }
    #pragma unroll
    for (int q = 0; q < 4; q++) {
        int row = row0 + hw * 4 + q;
        if (row < N) ybf[(size_t)row * 32 + hl] = pack_bf16x2(a0[q], a1[q]);
    }
}

// ---------------- scan phase 1: per-1024-chunk sums of bh ----------------
__global__ __launch_bounds__(256) void scan1_kernel(const int* __restrict__ bh, int M,
                                                    int* __restrict__ partials) {
    __shared__ int red[256];
    const int b = blockIdx.x, t = threadIdx.x;
    const int base = b * 1024;
    int s = 0;
    #pragma unroll
    for (int j = 0; j < 4; j++) {
        int idx = base + t * 4 + j;
        s += (idx < M) ? bh[idx] : 0;
    }
    red[t] = s; __syncthreads();
    for (int o = 128; o > 0; o >>= 1) { if (t < o) red[t] += red[t + o]; __syncthreads(); }
    if (t == 0) partials[b] = red[0];
}

// ---------------- scan phase 2: one-block LDS exclusive scan of partials ----------------
__global__ __launch_bounds__(256) void scan2_kernel(int* __restrict__ partials, int nb) {
    __shared__ int sb[2][256];
    const int t = threadIdx.x;
    int v = (t < nb) ? partials[t] : 0;
    sb[0][t] = v; __syncthreads();
    int c = 0;
    for (int o = 1; o < 256; o <<= 1) {
        int val = sb[c][t];
        if (t >= o) val += sb[c][t - o];
        sb[c ^ 1][t] = val; __syncthreads(); c ^= 1;
    }
    if (t < nb) partials[t] = sb[c][t] - v;   // exclusive
}

// ---------------- scan phase 3: chunk-local exclusive scan + base, in-place ----------------
__global__ __launch_bounds__(256) void scan3_kernel(int* __restrict__ bh, int M,
                                                    const int* __restrict__ partials) {
    __shared__ int sbuf[2][256];
    const int b = blockIdx.x, t = threadIdx.x;
    const int base = b * 1024;
    int v[4]; int s = 0;
    #pragma unroll
    for (int j = 0; j < 4; j++) {
        int idx = base + t * 4 + j;
        v[j] = (idx < M) ? bh[idx] : 0;
        s += v[j];
    }
    sbuf[0][t] = s; __syncthreads();
    int c = 0;
    for (int o = 1; o < 256; o <<= 1) {
        int val = sbuf[c][t];
        if (t >= o) val += sbuf[c][t - o];
        sbuf[c ^ 1][t] = val; __syncthreads(); c ^= 1;
    }
    int off = partials[b] + sbuf[c][t] - s;
    #pragma unroll
    for (int j = 0; j < 4; j++) {
        int idx = base + t * 4 + j;
        if (idx < M) bh[idx] = off;
        off += v[j];
    }
}

// ---------------- P3: partition edges into bucket runs (block-private, dense) ----------------
__global__ __launch_bounds__(256) void p3_part(const int* __restrict__ edges, long long E,
                                               int NB1, int B, const int* __restrict__ bh,
                                               unsigned* __restrict__ ebuf) {
    __shared__ int cur[B_MAX];
    const int i = blockIdx.x, t = threadIdx.x;
    for (int b = t; b < B; b += 256) cur[b] = bh[b * NB1 + i];
    __syncthreads();
    long long s0 = (long long)i * CSR_CHUNK;
    long long s1 = s0 + CSR_CHUNK; if (s1 > E) s1 = E;
    for (long long e = s0 + t; e < s1; e += 256) {
        int src = edges[e];
        int dst = edges[E + e];
        int b = dst >> 8;
        int pos = atomicAdd(&cur[b], 1);
        ebuf[pos] = (unsigned)src | ((unsigned)(dst & 255) << 24);
    }
}

// ---- P4: per-bucket padded CSR: node runs padded to mult-of-4 (min 4), gaps = N ----
__global__ __launch_bounds__(256) void p4_build(const unsigned* __restrict__ ebuf, long long E,
                                                int NB1, int B, const int* __restrict__ bh,
                                                int* __restrict__ offsets, int* __restrict__ psz,
                                                int* __restrict__ eidx, int N) {
    __shared__ unsigned lbuf[P4_CAP];
    __shared__ int hist[256];
    __shared__ int sbuf[2][256];
    __shared__ int cur[256];
    __shared__ int lstart[256];
    const int b = blockIdx.x, t = threadIdx.x;
    const int s = bh[b * NB1];
    const int e = (b + 1 < B) ? bh[(b + 1) * NB1] : (int)E;
    const int sz = e - s;
    const int ps = ((s + 3) & ~3) + b * BSPACE;
    const int next_raw = (b + 1 < B) ? bh[(b + 1) * NB1] : (int)E;
    const int next_ps = ((next_raw + 3) & ~3) + (b + 1) * BSPACE;
    const bool inl = (sz <= P4_CAP);
    if (inl) for (int k = t; k < sz; k += 256) lbuf[k] = ebuf[s + k];
    hist[t] = 0;
    __syncthreads();
    for (int k = t; k < sz; k += 256) {
        unsigned v = inl ? lbuf[k] : ebuf[s + k];
        atomicAdd(&hist[v >> 24], 1);
    }
    __syncthreads();
    const int deg = hist[t];
    const int pad = max(4, (deg + 3) & ~3);
    sbuf[0][t] = pad; __syncthreads();
    int c = 0;
    for (int o = 1; o < 256; o <<= 1) {
        int val = sbuf[c][t];
        if (t >= o) val += sbuf[c][t - o];
        sbuf[c ^ 1][t] = val; __syncthreads(); c ^= 1;
    }
    const int excl = sbuf[c][t] - pad;
    const int total = sbuf[c][255];
    const int node = b * 256 + t;
    if (node < N) { offsets[node] = ps + excl; psz[node] = pad; }
    lstart[t] = excl;
    cur[t] = 0;
    __syncthreads();
    for (int k = t; k < sz; k += 256) {
        unsigned v = inl ? lbuf[k] : ebuf[s + k];
        int dl = v >> 24;
        int pos = atomicAdd(&cur[dl], 1);
        eidx[ps + lstart[dl] + pos] = (int)(v & 0xFFFFFFu);
    }
    for (int k = deg; k < pad; k++) eidx[ps + excl + k] = N;
    __syncthreads();
    for (int i = ps + total + t; i < next_ps; i += 256) eidx[i] = N;
}

// ---- y = h @ w1 (bf16x2); FUSE: prev-layer BN computed inline + write back ----
template<int DIN, bool FUSE>
__global__ __launch_bounds__(256) void proj_kernel(
    const float* __restrict__ h, int h_stride, int h_off,
    float* __restrict__ h_back,
    const float* __restrict__ w1,
    const float* __restrict__ stats_prev,
    const float* __restrict__ gamma_prev, const float* __restrict__ beta_prev,
    unsigned* __restrict__ ybf, int N)
{
    constexpr int R = 32;
    __shared__ float w1s[DIN * DIM];
    __shared__ float hin[R][DIN];
    __shared__ float scshs[2 * DIM];
    const int tid = threadIdx.x;
    const int row0 = blockIdx.x * R;

    if (FUSE && tid < DIM) {
        float inv_n = 1.0f / (float)N;
        float mean = stats_prev[tid] * inv_n;
        float var  = stats_prev[DIM + tid] * inv_n - mean * mean;
        float sc   = gamma_prev[tid] * rsqrtf(var + BN_EPS);
        scshs[tid] = sc;
        scshs[DIM + tid] = beta_prev[tid] - mean * sc;
    }
    for (int i = tid; i < DIN * DIM / 4; i += 256)
        *(float4*)&w1s[i * 4] = *(const float4*)&w1[i * 4];
    if (FUSE) __syncthreads();
    for (int i = tid; i < R * DIN / 4; i += 256) {
        int r = i / (DIN / 4), k4 = (i % (DIN / 4)) * 4;
        int row = row0 + r;
        float4 hv = make_float4(0.f, 0.f, 0.f, 0.f);
        if (row < N) {
            hv = *(const float4*)&h[(size_t)row * h_stride + h_off + k4];
            if (FUSE) {
                hv.x = hv.x * scshs[k4 + 0] + scshs[DIM + k4 + 0];
                hv.y = hv.y * scshs[k4 + 1] + scshs[DIM + k4 + 1];
                hv.z = hv.z * scshs[k4 + 2] + scshs[DIM + k4 + 2];
                hv.w = hv.w * scshs[k4 + 3] + scshs[DIM + k4 + 3];
                *(float4*)&h_back[(size_t)row * h_stride + h_off + k4] = hv;
            }
        }
        *(float4*)&hin[r][k4] = hv;
    }
    __syncthreads();

    const int hw = tid >> 5;
    const int hl = tid & 31;
    float a0[4], a1[4];
    #pragma unroll
    for (int q = 0; q < 4; q++) { a0[q] = 0.f; a1[q] = 0.f; }
    for (int k = 0; k < DIN; k++) {
        float w0 = w1s[k * DIM + 2 * hl];
        float w1v = w1s[k * DIM + 2 * hl + 1];
        #pragma unroll
        for (int q = 0; q < 4; q++) {
            float hv = hin[hw * 4 + q][k];
            a0[q] += hv * w0; a1[q] += hv * w1v;
        }
    }
    #pragma unroll
    for (int q = 0; q < 4; q++) {
        int row = row0 + hw * 4 + q;
        if (row < N) ybf[(size_t)row * 32 + hl] = pack_bf16x2(a0[q], a1[q]);
    }
}

// ---- fused agg+MLP (quarter-wave, pipelined); optional merged poolA blocks ----
template<bool WITH_POOL>
__global__ __launch_bounds__(256) void aggmlp_kernel(
    const unsigned* __restrict__ ybf,
    const int* __restrict__ offsets, const int* __restrict__ psz,
    const int* __restrict__ eidx,
    const float* __restrict__ b1,
    const float* __restrict__ w2, const float* __restrict__ b2,
    float* __restrict__ xs, int xs_off,
    float* __restrict__ stats, int N,
    int ablocks, const int* __restrict__ batch, float* __restrict__ pool)
{
    constexpr int R = 64;
    __shared__ float zin[R][DIM];        // 16KB
    __shared__ float sred[2][DIM];
    const int tid  = threadIdx.x;

    if (WITH_POOL && blockIdx.x >= ablocks) {
        // ---------- poolA: sum cols 0..127 (already normalized) per graph ----------
        const int g = blockIdx.x - ablocks;
        const int half = tid >> 7, c = tid & 127;
        int lo = 0, hi = N;
        while (lo < hi) { int mid = (lo + hi) >> 1; if (batch[mid] < g) lo = mid + 1; else hi = mid; }
        int start = lo;
        hi = N;
        while (lo < hi) { int mid = (lo + hi) >> 1; if (batch[mid] < g + 1) lo = mid + 1; else hi = mid; }
        int end = lo;
        int mid2 = (start + end) >> 1;
        int rs = half ? mid2 : start;
        int re = half ? end : mid2;
        float s = 0.f;
        for (int n = rs; n < re; n++) s += xs[(size_t)n * XS_STRIDE + c];
        __shared__ float psum[2][128];
        psum[half][c] = s;
        __syncthreads();
        if (half == 0) pool[(size_t)g * XS_STRIDE + c] = psum[0][c] + psum[1][c];
        return;
    }

    const int row0 = blockIdx.x * R;
    const int qw = tid >> 4;
    const int ql = tid & 15;
    const uint2* __restrict__ ybf2 = (const uint2*)ybf;

    if (tid < DIM) { sred[0][tid] = 0.f; sred[1][tid] = 0.f; }

    const float4 b1v = *(const float4*)&b1[ql * 4];
    int p0[4], sz[4];
    float ac[4][4];
    #pragma unroll
    for (int q = 0; q < 4; q++) {
        int node = row0 + qw * 4 + q;
        if (node < N) {
            p0[q] = offsets[node];
            sz[q] = psz[node];
            uint2 sv = ybf2[(size_t)node * 16 + ql];
            float2 lo = unpack_bf16x2(sv.x), hi = unpack_bf16x2(sv.y);
            ac[q][0] = lo.x + b1v.x; ac[q][1] = lo.y + b1v.y;
            ac[q][2] = hi.x + b1v.z; ac[q][3] = hi.y + b1v.w;
        } else {
            p0[q] = 0; sz[q] = 0;
            ac[q][0] = ac[q][1] = ac[q][2] = ac[q][3] = 0.f;
        }
    }
    int steps = 0;
    #pragma unroll
    for (int q = 0; q < 4; q++) steps = max(steps, sz[q] >> 2);

    int4 e4[4];
    #pragma unroll
    for (int q = 0; q < 4; q++)
        e4[q] = *(const int4*)&eidx[p0[q]];

    for (int s = 0; s < steps; s++) {
        const int b4 = 4 * s;
        uint2 g[4][4];
        #pragma unroll
        for (int q = 0; q < 4; q++) {
            g[q][0] = ybf2[(size_t)e4[q].x * 16 + ql];
            g[q][1] = ybf2[(size_t)e4[q].y * 16 + ql];
            g[q][2] = ybf2[(size_t)e4[q].z * 16 + ql];
            g[q][3] = ybf2[(size_t)e4[q].w * 16 + ql];
        }
        int4 e4n[4];
        #pragma unroll
        for (int q = 0; q < 4; q++) {
            int off = max(0, min(b4 + 4, sz[q] - 4));
            e4n[q] = *(const int4*)&eidx[p0[q] + off];
        }
        #pragma unroll
        for (int q = 0; q < 4; q++) {
            const float m = (b4 < sz[q]) ? 1.f : 0.f;
            #pragma unroll
            for (int j = 0; j < 4; j++) {
                float2 lo = unpack_bf16x2(g[q][j].x), hi = unpack_bf16x2(g[q][j].y);
                ac[q][0] += lo.x * m; ac[q][1] += lo.y * m;
                ac[q][2] += hi.x * m; ac[q][3] += hi.y * m;
            }
        }
        #pragma unroll
        for (int q = 0; q < 4; q++) e4[q] = e4n[q];
    }
    #pragma unroll
    for (int q = 0; q < 4; q++) {
        int r = qw * 4 + q;
        float4 z;
        z.x = fmaxf(ac[q][0], 0.f); z.y = fmaxf(ac[q][1], 0.f);
        z.z = fmaxf(ac[q][2], 0.f); z.w = fmaxf(ac[q][3], 0.f);
        *(float4*)&zin[r][ql * 4] = z;
    }
    __syncthreads();

    const int lane = tid & 63;
    const int wv_  = tid >> 6;
    float oacc[16];
    #pragma unroll
    for (int i = 0; i < 16; i++) oacc[i] = b2[lane];
    for (int k = 0; k < DIM; k++) {
        float w = w2[k * DIM + lane];
        #pragma unroll
        for (int i = 0; i < 16; i++) oacc[i] += zin[wv_ + 4 * i][k] * w;
    }
    float s1 = 0.f, s2 = 0.f;
    #pragma unroll
    for (int i = 0; i < 16; i++) {
        int row = row0 + wv_ + 4 * i;
        if (row < N) {
            float v = fmaxf(oacc[i], 0.f);
            xs[(size_t)row * XS_STRIDE + xs_off + lane] = v;
            s1 += v; s2 += v * v;
        }
    }
    atomicAdd(&sred[0][lane], s1);
    atomicAdd(&sred[1][lane], s2);
    __syncthreads();
    if (tid < DIM) {
        atomicAdd(&stats[tid], sred[0][tid]);
        atomicAdd(&stats[DIM + tid], sred[1][tid]);
    }
}

// ---- poolB: cols 128..191 with layer-2 BN computed inline + write-back ----
__global__ void poolB_kernel(float* __restrict__ xs, const int* __restrict__ batch,
                             float* __restrict__ pool,
                             const float* __restrict__ stats2,
                             const float* __restrict__ gamma2, const float* __restrict__ beta2,
                             int N) {
    int g = blockIdx.x;
    int c = threadIdx.x;  // 64 threads
    float inv_n = 1.0f / (float)N;
    float mean = stats2[c] * inv_n;
    float var  = stats2[DIM + c] * inv_n - mean * mean;
    float sc = gamma2[c] * rsqrtf(var + BN_EPS);
    float sh = beta2[c] - mean * sc;
    int lo = 0, hi = N;
    while (lo < hi) { int mid = (lo + hi) >> 1; if (batch[mid] < g) lo = mid + 1; else hi = mid; }
    int start = lo;
    hi = N;
    while (lo < hi) { int mid = (lo + hi) >> 1; if (batch[mid] < g + 1) lo = mid + 1; else hi = mid; }
    int end = lo;
    float s = 0.f;
    for (int n = start; n < end; n++) {
        size_t p = (size_t)n * XS_STRIDE + 2 * DIM + c;
        float v = xs[p] * sc + sh;
        xs[p] = v;
        s += v;
    }
    pool[(size_t)g * XS_STRIDE + 2 * DIM + c] = s;
}

extern "C" void kernel_launch(void* const* d_in, const int* in_sizes, int n_in,
                              void* d_out, int out_size, void* d_ws, size_t ws_size,
                              hipStream_t stream) {
    const float* x     = (const float*)d_in[0];
    const int*   edges = (const int*)d_in[1];   // int32 (harness converts integer inputs)
    const int*   batch = (const int*)d_in[2];   // int32

    const int  N    = in_sizes[2];
    const long long E = in_sizes[1] / 2;
    const int  F_IN = in_sizes[0] / N;              // 128
    const int  G    = out_size / XS_STRIDE - N;     // 1000

    const float* W[3][6];
    for (int l = 0; l < 3; l++)
        for (int p = 0; p < 6; p++)
            W[l][p] = (const float*)d_in[4 + l * 6 + p];

    float* out_pool = (float*)d_out;                        // G x 192
    float* out_xs   = out_pool + (size_t)G * XS_STRIDE;     // N x 192

    const int B   = (N + 255) >> 8;
    const int NB1 = (int)((E + CSR_CHUNK - 1) / CSR_CHUNK);
    const int M   = B * NB1;                                // bh entries (~76K)
    const int nsc = (M + 1023) / 1024;                      // scan chunks (<=256)
    const int EPAD = (int)(((E + 3) & ~3LL) + (long long)B * BSPACE + 64);

    // workspace layout (~27 MB)
    unsigned* ybf  = (unsigned*)d_ws;                   // (N+1) x 32 u32 (12.8 MB)
    float* stats   = (float*)(ybf + (size_t)(N + 1) * 32);  // 3 x 256 floats
    int*   offsets = (int*)(stats + 3 * 256);           // N
    int*   psz     = offsets + N + 1;                   // N
    int*   eidx    = psz + N;                           // EPAD (~7 MB)
    unsigned* ebuf = (unsigned*)(eidx + EPAD);          // E (6.4 MB)
    int*   bh      = (int*)(ebuf + E);                  // M (~300 KB)
    int*   partials= bh + M;                            // nsc (<=256)

    const int pblocks = (N + 31) / 32;
    const int ablocks = (N + 63) / 64;

    // ---- CSR build; proj0 merged into P1; 3-phase parallel scan of bh ----
    p1proj_kernel<<<NB1 + pblocks, 256, 0, stream>>>(edges + E, E, NB1, B, bh, stats,
                                                     x, F_IN, W[0][0], ybf, N);
    scan1_kernel<<<nsc, 256, 0, stream>>>(bh, M, partials);
    scan2_kernel<<<1, 256, 0, stream>>>(partials, nsc);
    scan3_kernel<<<nsc, 256, 0, stream>>>(bh, M, partials);
    p3_part<<<NB1, 256, 0, stream>>>(edges, E, NB1, B, bh, ebuf);
    p4_build<<<B, 256, 0, stream>>>(ebuf, E, NB1, B, bh, offsets, psz, eidx, N);

    // layer 0
    aggmlp_kernel<false><<<ablocks, 256, 0, stream>>>(ybf, offsets, psz, eidx,
        W[0][1], W[0][2], W[0][3], out_xs, 0, stats, N, ablocks, nullptr, nullptr);

    // layer 1
    proj_kernel<64, true><<<pblocks, 256, 0, stream>>>(
        out_xs, XS_STRIDE, 0, out_xs, W[1][0], stats, W[0][4], W[0][5], ybf, N);
    aggmlp_kernel<false><<<ablocks, 256, 0, stream>>>(ybf, offsets, psz, eidx,
        W[1][1], W[1][2], W[1][3], out_xs, DIM, stats + 256, N, ablocks, nullptr, nullptr);

    // layer 2 (+ poolA merged: cols 0..127 of per-graph sums)
    proj_kernel<64, true><<<pblocks, 256, 0, stream>>>(
        out_xs, XS_STRIDE, DIM, out_xs, W[2][0], stats + 256, W[1][4], W[1][5], ybf, N);
    aggmlp_kernel<true><<<ablocks + G, 256, 0, stream>>>(ybf, offsets, psz, eidx,
        W[2][1], W[2][2], W[2][3], out_xs, 2 * DIM, stats + 512, N, ablocks, batch, out_pool);

    // remaining pool cols 128..191 (need layer-2 stats)
    poolB_kernel<<<G, DIM, 0, stream>>>(out_xs, batch, out_pool,
                                        stats + 512, W[2][4], W[2][5], N);
}